// Round 5
// baseline (726.260 us; speedup 1.0000x reference)
//
#include <hip/hip_runtime.h>
#include <hip/hip_bf16.h>

#define N_NODES 10000
#define E_TOT   320000

typedef __attribute__((ext_vector_type(8))) short short8;
typedef __attribute__((ext_vector_type(4))) float f32x4;

// ---- workspace byte offsets (16B-aligned, total 104,973,576 < proven 107 MB) ----
#define AGG_S_OFF   0u            // N*256 f32 = 10,240,000 (zeroed)
#define AP_OFF      10240000u     // N*204 f32 =  8,160,000 (zeroed)  sum P[src] per dst
#define AEV_OFF     18400000u     // N*12  f32 =    480,000 (zeroed)  sum edge_v per dst
#define HIST_OFF    18880000u     // N int (zeroed)
#define FILL_OFF    18920000u     // N int (zeroed)
#define ZERO_BYTES  18960000u     // memset [0, here)
#define ROWPTR_OFF  18960000u     // (N+1) int, fully written by scan
#define PERM_OFF    19000064u     // E int
#define PSRC_OFF    20280064u     // E int
#define PDST_OFF    21560064u     // E int
#define PQ_OFF      22840064u     // N*416 bf16 = 8,320,000  [P(204)+pad4 | Q(204)+pad4]
#define QV_OFF      31160064u     // N*96 bf16 = 1,920,000   Qv for finalize
#define NS2_OFF     33080064u     // N*256 bf16 = 5,120,000
#define WHV4_OFF    38200064u     // 128 f32
#define WT_OFF      38200576u     // 256*416 bf16 = 212,992
#define NSBF_OFF    38413568u     // N*256 bf16 = 5,120,000 (dead after gemm)
#define AGGV_OFF    38413568u     // ALIAS: N*96 f32 = 3,840,000, written by nodev after gemm
#define VN_OFF      43533568u     // E*96 bf16 = 61,440,000 (sorted order)
#define FLAGS_OFF   104973568u    // 2 ints

union BfS { __hip_bfloat16 h; short s; };
__device__ __forceinline__ short f2bf(float x) { BfS u; u.h = __float2bfloat16(x); return u.s; }
__device__ __forceinline__ float bf(short x) { BfS u; u.s = x; return __bfloat162float(u.h); }
__device__ __forceinline__ float ldin(const void* p, int f32m, long i) {
  return f32m ? ((const float*)p)[i] : __bfloat162float(((const __hip_bfloat16*)p)[i]);
}
__device__ __forceinline__ int get_ei(const void* p, int i64m, long i) {
  return i64m ? (int)(((const long long*)p)[i]) : ((const int*)p)[i];
}

// ---------------------------------------------------------------------------
__global__ __launch_bounds__(256) void detect_kernel(
    const unsigned short* __restrict__ ns_u16,
    const int* __restrict__ ei_i32, int* __restrict__ flags)
{
  __shared__ int cf, ci;
  if (threadIdx.x == 0) { cf = 0; ci = 0; }
  __syncthreads();
  int c1 = 0;
  for (int i = threadIdx.x; i < 8192; i += 256) {
    unsigned e = (ns_u16[2 * i] >> 7) & 0xFF;
    if (e < 100 || e > 140) c1++;
  }
  int c2 = 0;
  for (int i = threadIdx.x; i < 4096; i += 256)
    if (ei_i32[2 * i + 1] != 0) c2++;
  atomicAdd(&cf, c1); atomicAdd(&ci, c2);
  __syncthreads();
  if (threadIdx.x == 0) {
    flags[0] = (cf > 512) ? 1 : 0;   // 1 => f32 inputs
    flags[1] = (ci < 100) ? 1 : 0;   // 1 => int64 edge_index
  }
}

// ---------------------------------------------------------------------------
__global__ __launch_bounds__(256) void hist_kernel(
    const void* __restrict__ edge_index, const int* __restrict__ flags,
    int* __restrict__ hist)
{
  const int i64m = flags[1];
  int e = blockIdx.x * 256 + threadIdx.x;
  int dst = get_ei(edge_index, i64m, (long)E_TOT + e);
  atomicAdd(&hist[dst], 1);
}

__global__ __launch_bounds__(256) void scan_kernel(
    const int* __restrict__ hist, int* __restrict__ rowptr)
{
  __shared__ int part[256];
  int tid = threadIdx.x;
  int base = tid * 40;
  int s = 0;
  for (int i = 0; i < 40; ++i) { int idx = base + i; if (idx < N_NODES) s += hist[idx]; }
  part[tid] = s;
  __syncthreads();
  for (int off = 1; off < 256; off <<= 1) {
    int v = (tid >= off) ? part[tid - off] : 0;
    __syncthreads();
    part[tid] += v;
    __syncthreads();
  }
  int run = (tid > 0) ? part[tid - 1] : 0;
  for (int i = 0; i < 40; ++i) {
    int idx = base + i;
    if (idx < N_NODES) { rowptr[idx] = run; run += hist[idx]; }
  }
  if (tid == 255) rowptr[N_NODES] = run;
}

__global__ __launch_bounds__(256) void permute_kernel(
    const void* __restrict__ edge_index, const int* __restrict__ flags,
    const int* __restrict__ rowptr, int* __restrict__ fill,
    int* __restrict__ perm, int* __restrict__ psrc, int* __restrict__ pdst)
{
  const int i64m = flags[1];
  int e = blockIdx.x * 256 + threadIdx.x;
  int dst = get_ei(edge_index, i64m, (long)E_TOT + e);
  int src = get_ei(edge_index, i64m, e);
  int pos = rowptr[dst] + atomicAdd(&fill[dst], 1);
  perm[pos] = e; psrc[pos] = src; pdst[pos] = dst;
}

// ---------------------------------------------------------------------------
__global__ __launch_bounds__(256) void prep_kernel(
    const void* __restrict__ ws_w, const void* __restrict__ wh,
    const void* __restrict__ wv, const int* __restrict__ flags,
    short* __restrict__ Wt, float* __restrict__ whv4)
{
  const int f32m = flags[0];
  int b = blockIdx.x, tid = threadIdx.x;
  if (b < 416) {
    int flat = b * 256 + tid;
    int n = flat / 416, k = flat % 416;
    short v = 0;
    if (k < 320)      v = f2bf(ldin(ws_w, f32m, (long)k * 256 + n));
    else if (k < 388) v = f2bf(ldin(ws_w, f32m, (long)(k + 256) * 256 + n));
    Wt[flat] = v;
  } else if (tid < 128) {
    int q = tid / 32, c = tid % 32;
    float acc = 0.f;
    for (int h = 0; h < 68; ++h)
      acc += ldin(wh, f32m, (32 + q) * 68 + h) * ldin(wv, f32m, h * 32 + c);
    whv4[tid] = acc;
  }
}

__global__ __launch_bounds__(256) void nsconv_kernel(
    const void* __restrict__ node_s, const int* __restrict__ flags,
    short* __restrict__ ns_bf)
{
  const int f32m = flags[0];
  int i = blockIdx.x * 256 + threadIdx.x;
  ns_bf[i] = f2bf(ldin(node_s, f32m, i));
}

// ---------------------------------------------------------------------------
// node_pre: per 4 nodes — PQ = [P|Q] (node_v^T @ wh halves, padded 208 each),
// Qv bf16 (Q-half @ wv), ns2 bf16 (node_s @ ws_w[320:576]).
// ---------------------------------------------------------------------------
__global__ __launch_bounds__(256) void node_pre(
    const void* __restrict__ node_s, const void* __restrict__ node_v,
    const void* __restrict__ wh, const void* __restrict__ wv,
    const void* __restrict__ ws_w, const int* __restrict__ flags,
    short* __restrict__ PQ, short* __restrict__ QV, short* __restrict__ ns2)
{
  const int f32m = flags[0];
  int n0 = blockIdx.x * 4, tid = threadIdx.x;
  __shared__ float nv[4][96];
  __shared__ float nsl[4][256];
  __shared__ float pq[4][408];
  for (int i = tid; i < 4 * 96; i += 256)  nv[i / 96][i % 96]    = ldin(node_v, f32m, (long)n0 * 96 + i);
  for (int i = tid; i < 4 * 256; i += 256) nsl[i / 256][i % 256] = ldin(node_s, f32m, (long)n0 * 256 + i);
  __syncthreads();
  for (int o = tid; o < 4 * 408; o += 256) {
    int i = o / 408, r0 = o % 408;
    int part = r0 / 204, r = r0 % 204, d = r / 68, h = r % 68;
    int cbase = part ? 36 : 0;
    float acc = 0.f;
#pragma unroll
    for (int c = 0; c < 32; ++c)
      acc += nv[i][c * 3 + d] * ldin(wh, f32m, (cbase + c) * 68 + h);
    pq[i][r0] = acc;
  }
  __syncthreads();
  // PQ with pads (layout [part*208 + r], r<204 valid)
  for (int o = tid; o < 4 * 416; o += 256) {
    int i = o / 416, k = o % 416, part = k / 208, r = k % 208;
    PQ[(long)(n0 + i) * 416 + k] = (r < 204) ? f2bf(pq[i][part * 204 + r]) : (short)0;
  }
  // Qv[n][d*32+c]
  for (int o = tid; o < 4 * 96; o += 256) {
    int i = o / 96, r = o % 96, d = r / 32, c = r % 32;
    float acc = 0.f;
    for (int h = 0; h < 68; ++h)
      acc += pq[i][204 + d * 68 + h] * ldin(wv, f32m, h * 32 + c);
    QV[(long)(n0 + i) * 96 + r] = f2bf(acc);
  }
  {
    float a0 = 0.f, a1 = 0.f, a2 = 0.f, a3 = 0.f;
    for (int k = 0; k < 256; ++k) {
      float w = ldin(ws_w, f32m, (long)(320 + k) * 256 + tid);
      a0 += nsl[0][k] * w; a1 += nsl[1][k] * w;
      a2 += nsl[2][k] * w; a3 += nsl[3][k] * w;
    }
    ns2[(long)(n0 + 0) * 256 + tid] = f2bf(a0); ns2[(long)(n0 + 1) * 256 + tid] = f2bf(a1);
    ns2[(long)(n0 + 2) * 256 + tid] = f2bf(a2); ns2[(long)(n0 + 3) * 256 + tid] = f2bf(a3);
  }
}

// ---------------------------------------------------------------------------
// edge_tile: 64 sorted edges/block. Vectorized P/Q row staging, vn to LDS then
// coalesced write, AP/AEV accumulated with run-merged atomics.
// ---------------------------------------------------------------------------
__global__ __launch_bounds__(256) void edge_tile(
    const void* __restrict__ edge_v, const void* __restrict__ wh,
    const int* __restrict__ flags,
    const int* __restrict__ perm, const int* __restrict__ psrc,
    const int* __restrict__ pdst, const short* __restrict__ PQ,
    float* __restrict__ AP, float* __restrict__ AEV,
    short* __restrict__ vn_out)
{
  const int f32m = flags[0];
  const int tid = threadIdx.x;
  const int e0 = blockIdx.x * 64;
  __shared__ __align__(16) short Ps[64 * 208];
  __shared__ __align__(16) short Qs[64 * 208];
  __shared__ __align__(16) short vns[64 * 96];
  __shared__ float ev[64 * 12];
  __shared__ float whs4[272];
  __shared__ int sv[64], dv[64], eidv[64], qrow[64];
  if (tid < 64) { sv[tid] = psrc[e0 + tid]; dv[tid] = pdst[e0 + tid]; eidv[tid] = perm[e0 + tid]; }
  for (int i = tid; i < 272; i += 256) whs4[i] = ldin(wh, f32m, (32 + i / 68) * 68 + i % 68);
  __syncthreads();
  if (tid == 0) {
    qrow[0] = 0;
    for (int i = 1; i < 64; ++i) qrow[i] = (dv[i] == dv[i - 1]) ? qrow[i - 1] : i;
  }
  for (int o = tid; o < 64 * 26; o += 256) {
    int e = o / 26, c = o % 26;
    *(short8*)&Ps[e * 208 + c * 8] = *(const short8*)&PQ[(long)sv[e] * 416 + c * 8];
  }
  for (int i = tid; i < 64 * 12; i += 256)
    ev[i] = ldin(edge_v, f32m, (long)eidv[i / 12] * 12 + i % 12);
  __syncthreads();           // qrow + Ps + ev ready
  for (int o = tid; o < 64 * 26; o += 256) {
    int e = o / 26, c = o % 26;
    if (qrow[e] == e)
      *(short8*)&Qs[e * 208 + c * 8] = *(const short8*)&PQ[(long)dv[e] * 416 + 208 + c * 8];
  }
  __syncthreads();
  for (int o = tid; o < 64 * 68; o += 256) {
    int e = o / 68, h = o % 68, qe = qrow[e];
    float ss = 0.f;
#pragma unroll
    for (int d = 0; d < 3; ++d) {
      float v = bf(Ps[e * 208 + d * 68 + h]) + bf(Qs[qe * 208 + d * 68 + h])
              + ev[e * 12 + d]     * whs4[h]       + ev[e * 12 + 3 + d] * whs4[68 + h]
              + ev[e * 12 + 6 + d] * whs4[136 + h] + ev[e * 12 + 9 + d] * whs4[204 + h];
      ss += v * v;
    }
    vns[e * 96 + h] = f2bf(sqrtf(fmaxf(ss, 1e-8f)));
  }
  for (int o = tid; o < 64 * 28; o += 256)
    vns[(o / 28) * 96 + 68 + o % 28] = 0;
  __syncthreads();
  for (int o = tid; o < 768; o += 256)
    *(short8*)&vn_out[(long)e0 * 96 + o * 8] = *(const short8*)&vns[o * 8];
  // AP (cols 0..203) and AEV (cols 0..11) run-merged scatter
  if (tid < 204) {
    float run = 0.f; int cur = dv[0];
    for (int e = 0; e < 64; ++e) {
      int dn = dv[e];
      if (dn != cur) { atomicAdd(&AP[(long)cur * 204 + tid], run); run = 0.f; cur = dn; }
      run += bf(Ps[e * 208 + tid]);
    }
    atomicAdd(&AP[(long)cur * 204 + tid], run);
  } else if (tid < 216) {
    int c = tid - 204;
    float run = 0.f; int cur = dv[0];
    for (int e = 0; e < 64; ++e) {
      int dn = dv[e];
      if (dn != cur) { atomicAdd(&AEV[(long)cur * 12 + c], run); run = 0.f; cur = dn; }
      run += ev[e * 12 + c];
    }
    atomicAdd(&AEV[(long)cur * 12 + c], run);
  }
}

// ---------------------------------------------------------------------------
// gemm_scatter: 128 sorted edges/block x 256 cols, K=416, MFMA 16x16x32 bf16.
// Each wave: 8 row-frags x 4 col-tiles (32 MFMA per K-slab).
// ---------------------------------------------------------------------------
__global__ __launch_bounds__(256, 2) void gemm_scatter(
    const short* __restrict__ ns_bf, const void* __restrict__ edge_s,
    const short* __restrict__ Wt, const short* __restrict__ vn_ws,
    const int* __restrict__ perm, const int* __restrict__ psrc,
    const int* __restrict__ pdst, const int* __restrict__ flags,
    float* __restrict__ agg_s)
{
  __shared__ __align__(16) short Xs[128 * 40];
  __shared__ __align__(16) short Ws[256 * 40];
  __shared__ int srcv[128], dstv[128], eidv[128];
  const int tid = threadIdx.x;
  const int e0 = blockIdx.x * 128;
  const int f32m = flags[0];
  if (tid < 128) {
    srcv[tid] = psrc[e0 + tid];
    dstv[tid] = pdst[e0 + tid];
    eidv[tid] = perm[e0 + tid];
  }
  __syncthreads();
  const int lane = tid & 63, wave = tid >> 6;
  const int frow = lane & 15, fk = (lane >> 4) * 8, q = lane >> 4;
  f32x4 acc[8][4];
#pragma unroll
  for (int ri = 0; ri < 8; ++ri)
#pragma unroll
    for (int ci = 0; ci < 4; ++ci)
      acc[ri][ci] = (f32x4){0.f, 0.f, 0.f, 0.f};

  const int se = tid >> 1;          // row 0..127
  const int sq0 = (tid & 1) * 2;    // chunks sq0, sq0+1

  for (int s = 0; s < 13; ++s) {
#pragma unroll
    for (int c = 0; c < 2; ++c) {
      int sq = sq0 + c;
      short8 xv;
      if (s < 8) {
        xv = *(const short8*)&ns_bf[(long)srcv[se] * 256 + s * 32 + sq * 8];
      } else if (s < 10) {
        long off = (long)eidv[se] * 64 + (s - 8) * 32 + sq * 8;
        if (f32m) {
          const float* pf = (const float*)edge_s + off;
          f32x4 lo = *(const f32x4*)pf, hi = *(const f32x4*)(pf + 4);
          xv[0] = f2bf(lo[0]); xv[1] = f2bf(lo[1]); xv[2] = f2bf(lo[2]); xv[3] = f2bf(lo[3]);
          xv[4] = f2bf(hi[0]); xv[5] = f2bf(hi[1]); xv[6] = f2bf(hi[2]); xv[7] = f2bf(hi[3]);
        } else {
          xv = *(const short8*)((const short*)edge_s + off);
        }
      } else {
        xv = *(const short8*)&vn_ws[(long)(e0 + se) * 96 + (s - 10) * 32 + sq * 8];
      }
      *(short8*)&Xs[se * 40 + sq * 8] = xv;
    }
#pragma unroll
    for (int it = 0; it < 4; ++it) {
      int flat = it * 256 + tid;
      int nn = flat >> 2, qq = flat & 3;
      *(short8*)&Ws[nn * 40 + qq * 8] = *(const short8*)&Wt[nn * 416 + s * 32 + qq * 8];
    }
    __syncthreads();
    short8 a[8];
#pragma unroll
    for (int ri = 0; ri < 8; ++ri)
      a[ri] = *(const short8*)&Xs[(ri * 16 + frow) * 40 + fk];
#pragma unroll
    for (int ci = 0; ci < 4; ++ci) {
      int nn = wave * 64 + ci * 16 + frow;
      short8 b = *(const short8*)&Ws[nn * 40 + fk];
#pragma unroll
      for (int ri = 0; ri < 8; ++ri)
        acc[ri][ci] = __builtin_amdgcn_mfma_f32_16x16x32_bf16(a[ri], b, acc[ri][ci], 0, 0, 0);
    }
    __syncthreads();
  }
  // epilogue: lane rows {16*ri + 4*q + rr} monotone; run-merge on sorted dst.
#pragma unroll
  for (int ci = 0; ci < 4; ++ci) {
    int col = wave * 64 + ci * 16 + (lane & 15);
    float run = 0.f;
    int cur = dstv[4 * q];
#pragma unroll
    for (int ri = 0; ri < 8; ++ri) {
#pragma unroll
      for (int rr = 0; rr < 4; ++rr) {
        int dn = dstv[16 * ri + 4 * q + rr];
        if (dn != cur) {
          atomicAdd(&agg_s[(long)cur * 256 + col], run);
          run = 0.f; cur = dn;
        }
        run += acc[ri][ci][rr];
      }
    }
    atomicAdd(&agg_s[(long)cur * 256 + col], run);
  }
}

// ---------------------------------------------------------------------------
// nodev: agg_v[n] = AP[n] @ wv + AEV[n] @ whv4   (4 nodes/block)
// ---------------------------------------------------------------------------
__global__ __launch_bounds__(256) void nodev_kernel(
    const float* __restrict__ AP, const float* __restrict__ AEV,
    const void* __restrict__ wv, const float* __restrict__ whv4,
    const int* __restrict__ flags, float* __restrict__ agg_v)
{
  const int f32m = flags[0];
  int n0 = blockIdx.x * 4, tid = threadIdx.x;
  __shared__ float wvs[68 * 32];
  __shared__ float wh4s[128];
  __shared__ float APs[4][204];
  __shared__ float AEVs[4][12];
  for (int i = tid; i < 2176; i += 256) wvs[i] = ldin(wv, f32m, i);
  if (tid < 128) wh4s[tid] = whv4[tid];
  for (int i = tid; i < 816; i += 256) APs[i / 204][i % 204] = AP[(long)n0 * 204 + i];
  if (tid < 48) AEVs[tid / 12][tid % 12] = AEV[(long)n0 * 12 + tid];
  __syncthreads();
  for (int o = tid; o < 384; o += 256) {
    int i = o / 96, r = o % 96, c = r / 3, d = r % 3;
    float acc = AEVs[i][d] * wh4s[c] + AEVs[i][3 + d] * wh4s[32 + c]
              + AEVs[i][6 + d] * wh4s[64 + c] + AEVs[i][9 + d] * wh4s[96 + c];
    for (int h = 0; h < 68; ++h)
      acc += APs[i][d * 68 + h] * wvs[h * 32 + c];
    agg_v[(long)(n0 + i) * 96 + r] = acc;
  }
}

// ---------------------------------------------------------------------------
__global__ __launch_bounds__(256) void finalize(
    const float* __restrict__ agg_s, const float* __restrict__ agg_v,
    const int* __restrict__ rowptr, const short* __restrict__ ns2,
    const short* __restrict__ QV, const void* __restrict__ ws_b,
    const int* __restrict__ flags, void* __restrict__ out)
{
  const int f32m = flags[0];
  int flat = blockIdx.x * 256 + threadIdx.x;   // N*352 exact
  int n = flat / 352, j = flat % 352;
  int deg = rowptr[n + 1] - rowptr[n];
  float inv = 1.f / fmaxf((float)deg, 1.f);
  float v;
  if (j < 256) {
    v = agg_s[(long)n * 256 + j] * inv;
    if (deg > 0) v += bf(ns2[(long)n * 256 + j]) + ldin(ws_b, f32m, j);
  } else {
    int m = j - 256, ch = m / 3, d = m % 3;
    v = agg_v[(long)n * 96 + m] * inv;
    if (deg > 0) v += bf(QV[(long)n * 96 + d * 32 + ch]);
  }
  if (f32m) ((float*)out)[flat] = v;
  else      ((__hip_bfloat16*)out)[flat] = __float2bfloat16(v);
}

extern "C" void kernel_launch(void* const* d_in, const int* in_sizes, int n_in,
                              void* d_out, int out_size, void* d_ws, size_t ws_size,
                              hipStream_t stream) {
  const void* node_s = d_in[0];
  const void* node_v = d_in[1];
  const void* edge_s = d_in[2];
  const void* edge_v = d_in[3];
  const void* wh     = d_in[4];
  const void* ws_w   = d_in[5];
  const void* ws_b   = d_in[6];
  const void* wv     = d_in[7];
  const void* edge_index = d_in[8];

  char* ws = (char*)d_ws;
  float* agg_s = (float*)(ws + AGG_S_OFF);
  float* AP    = (float*)(ws + AP_OFF);
  float* AEV   = (float*)(ws + AEV_OFF);
  int*   hist  = (int*)(ws + HIST_OFF);
  int*   fill  = (int*)(ws + FILL_OFF);
  int*   rowptr= (int*)(ws + ROWPTR_OFF);
  int*   perm  = (int*)(ws + PERM_OFF);
  int*   psrc  = (int*)(ws + PSRC_OFF);
  int*   pdst  = (int*)(ws + PDST_OFF);
  short* PQ    = (short*)(ws + PQ_OFF);
  short* QV    = (short*)(ws + QV_OFF);
  short* ns2   = (short*)(ws + NS2_OFF);
  float* whv4  = (float*)(ws + WHV4_OFF);
  short* Wt    = (short*)(ws + WT_OFF);
  short* ns_bf = (short*)(ws + NSBF_OFF);
  float* agg_v = (float*)(ws + AGGV_OFF);   // aliases ns_bf (dead after gemm)
  short* vn    = (short*)(ws + VN_OFF);
  int*   flags = (int*)(ws + FLAGS_OFF);

  hipMemsetAsync(d_ws, 0, ZERO_BYTES, stream);
  detect_kernel<<<1, 256, 0, stream>>>((const unsigned short*)node_s,
                                       (const int*)edge_index, flags);
  hist_kernel<<<1250, 256, 0, stream>>>(edge_index, flags, hist);
  scan_kernel<<<1, 256, 0, stream>>>(hist, rowptr);
  permute_kernel<<<1250, 256, 0, stream>>>(edge_index, flags, rowptr, fill,
                                           perm, psrc, pdst);
  prep_kernel<<<417, 256, 0, stream>>>(ws_w, wh, wv, flags, Wt, whv4);
  nsconv_kernel<<<10000, 256, 0, stream>>>(node_s, flags, ns_bf);
  node_pre<<<2500, 256, 0, stream>>>(node_s, node_v, wh, wv, ws_w, flags,
                                     PQ, QV, ns2);
  edge_tile<<<5000, 256, 0, stream>>>(edge_v, wh, flags, perm, psrc, pdst,
                                      PQ, AP, AEV, vn);
  gemm_scatter<<<2500, 256, 0, stream>>>(ns_bf, edge_s, Wt, vn, perm, psrc,
                                         pdst, flags, agg_s);
  nodev_kernel<<<2500, 256, 0, stream>>>(AP, AEV, wv, whv4, flags, agg_v);
  finalize<<<13750, 256, 0, stream>>>(agg_s, agg_v, rowptr, ns2, QV, ws_b,
                                      flags, d_out);
}

// Round 6
// 576.935 us; speedup vs baseline: 1.2588x; 1.2588x over previous
//
#include <hip/hip_runtime.h>
#include <hip/hip_bf16.h>

#define N_NODES 10000
#define E_TOT   320000

typedef __attribute__((ext_vector_type(8))) short short8;
typedef __attribute__((ext_vector_type(4))) float f32x4;

// ---- workspace byte offsets (16B-aligned; total 105,104,712 < proven 107 MB) ----
#define AGG_S_OFF   0u            // N*256 f32 = 10,240,000 (zeroed; edge-part only)
#define HIST_OFF    10240000u     // N int (zeroed)
#define FILL_OFF    10280000u     // N int (zeroed)
#define ZERO_BYTES  10320000u     // memset [0, here)
#define ROWPTR_OFF  10320064u     // (N+1) int
#define PERM_OFF    10360128u     // E int
#define PSRC_OFF    11640128u     // E int
#define PDST_OFF    12920128u     // E int
#define PQ_OFF      14200128u     // N*416 bf16 [P(204)+pad | Q(204)+pad]
#define QV_OFF      22520128u     // N*96 bf16
#define WHV4_OFF    24440128u     // 128 f32
#define WT3_OFF     24440640u     // 256*160 bf16 = 81,920   edge-GEMM W
#define W12T_OFF    24522560u     // 256*512 bf16 = 262,144  node-GEMM W
#define NSBF_OFF    24784704u     // N*256 bf16 = 5,120,000 (dead after node_gemm)
#define AGGV_OFF    24784704u     // ALIAS: N*96 f32, written by nodev AFTER node_gemm
#define ANSB_OFF    29904704u     // N*256 bf16 = 5,120,000  (ANS/deg)
#define AP_OFF      35024704u     // N*204 f32 = 8,160,000   (direct write)
#define AEV_OFF     43184704u     // N*12 f32 = 480,000      (direct write)
#define NODES_OFF   43664704u     // N*256 f32 = 10,240,000  NodeS
#define VN_OFF      53904704u     // E*80 bf16 = 51,200,000 (sorted; cols 68..79 = 0)
#define FLAGS_OFF   105104704u    // 2 ints

union BfS { __hip_bfloat16 h; short s; };
__device__ __forceinline__ short f2bf(float x) { BfS u; u.h = __float2bfloat16(x); return u.s; }
__device__ __forceinline__ float bf(short x) { BfS u; u.s = x; return __bfloat162float(u.h); }
__device__ __forceinline__ float ldin(const void* p, int f32m, long i) {
  return f32m ? ((const float*)p)[i] : __bfloat162float(((const __hip_bfloat16*)p)[i]);
}
__device__ __forceinline__ int get_ei(const void* p, int i64m, long i) {
  return i64m ? (int)(((const long long*)p)[i]) : ((const int*)p)[i];
}

// ---------------------------------------------------------------------------
__global__ __launch_bounds__(256) void detect_kernel(
    const unsigned short* __restrict__ ns_u16,
    const int* __restrict__ ei_i32, int* __restrict__ flags)
{
  __shared__ int cf, ci;
  if (threadIdx.x == 0) { cf = 0; ci = 0; }
  __syncthreads();
  int c1 = 0;
  for (int i = threadIdx.x; i < 8192; i += 256) {
    unsigned e = (ns_u16[2 * i] >> 7) & 0xFF;
    if (e < 100 || e > 140) c1++;
  }
  int c2 = 0;
  for (int i = threadIdx.x; i < 4096; i += 256)
    if (ei_i32[2 * i + 1] != 0) c2++;
  atomicAdd(&cf, c1); atomicAdd(&ci, c2);
  __syncthreads();
  if (threadIdx.x == 0) {
    flags[0] = (cf > 512) ? 1 : 0;   // 1 => f32 inputs
    flags[1] = (ci < 100) ? 1 : 0;   // 1 => int64 edge_index
  }
}

// ---------------------------------------------------------------------------
__global__ __launch_bounds__(256) void hist_kernel(
    const void* __restrict__ edge_index, const int* __restrict__ flags,
    int* __restrict__ hist)
{
  const int i64m = flags[1];
  int e = blockIdx.x * 256 + threadIdx.x;
  int dst = get_ei(edge_index, i64m, (long)E_TOT + e);
  atomicAdd(&hist[dst], 1);
}

__global__ __launch_bounds__(256) void scan_kernel(
    const int* __restrict__ hist, int* __restrict__ rowptr)
{
  __shared__ int part[256];
  int tid = threadIdx.x;
  int base = tid * 40;
  int s = 0;
  for (int i = 0; i < 40; ++i) { int idx = base + i; if (idx < N_NODES) s += hist[idx]; }
  part[tid] = s;
  __syncthreads();
  for (int off = 1; off < 256; off <<= 1) {
    int v = (tid >= off) ? part[tid - off] : 0;
    __syncthreads();
    part[tid] += v;
    __syncthreads();
  }
  int run = (tid > 0) ? part[tid - 1] : 0;
  for (int i = 0; i < 40; ++i) {
    int idx = base + i;
    if (idx < N_NODES) { rowptr[idx] = run; run += hist[idx]; }
  }
  if (tid == 255) rowptr[N_NODES] = run;
}

__global__ __launch_bounds__(256) void permute_kernel(
    const void* __restrict__ edge_index, const int* __restrict__ flags,
    const int* __restrict__ rowptr, int* __restrict__ fill,
    int* __restrict__ perm, int* __restrict__ psrc, int* __restrict__ pdst)
{
  const int i64m = flags[1];
  int e = blockIdx.x * 256 + threadIdx.x;
  int dst = get_ei(edge_index, i64m, (long)E_TOT + e);
  int src = get_ei(edge_index, i64m, e);
  int pos = rowptr[dst] + atomicAdd(&fill[dst], 1);
  perm[pos] = e; psrc[pos] = src; pdst[pos] = dst;
}

// ---------------------------------------------------------------------------
// prep: W12t[o][k<512] (k<256: ws_w rows 0..255; else rows 320..575),
//       Wt3[o][k<160]  (k<64: rows 256..319; 64..131: rows 576..643; else 0),
//       whv4 = wh[32:36] @ wv.
// ---------------------------------------------------------------------------
__global__ __launch_bounds__(256) void prep_kernel(
    const void* __restrict__ ws_w, const void* __restrict__ wh,
    const void* __restrict__ wv, const int* __restrict__ flags,
    short* __restrict__ W12t, short* __restrict__ Wt3, float* __restrict__ whv4)
{
  const int f32m = flags[0];
  int b = blockIdx.x, tid = threadIdx.x;
  if (b < 512) {
    int flat = b * 256 + tid;           // = o*512 + k
    int o = flat >> 9, k = flat & 511;
    int r = (k < 256) ? k : (320 + k - 256);
    W12t[flat] = f2bf(ldin(ws_w, f32m, (long)r * 256 + o));
  } else if (b < 672) {
    int flat = (b - 512) * 256 + tid;   // = o*160 + k
    int o = flat / 160, k = flat % 160;
    short v = 0;
    if (k < 64)       v = f2bf(ldin(ws_w, f32m, (long)(256 + k) * 256 + o));
    else if (k < 132) v = f2bf(ldin(ws_w, f32m, (long)(576 + k - 64) * 256 + o));
    Wt3[flat] = v;
  } else if (tid < 128) {
    int q = tid / 32, c = tid % 32;
    float acc = 0.f;
    for (int h = 0; h < 68; ++h)
      acc += ldin(wh, f32m, (32 + q) * 68 + h) * ldin(wv, f32m, h * 32 + c);
    whv4[tid] = acc;
  }
}

__global__ __launch_bounds__(256) void nsconv_kernel(
    const void* __restrict__ node_s, const int* __restrict__ flags,
    short* __restrict__ ns_bf)
{
  const int f32m = flags[0];
  int i = blockIdx.x * 256 + threadIdx.x;
  ns_bf[i] = f2bf(ldin(node_s, f32m, i));
}

// ---------------------------------------------------------------------------
// node_pre: per 4 nodes — PQ = [P|Q] bf16 (padded 208 each), Qv bf16.
// ---------------------------------------------------------------------------
__global__ __launch_bounds__(256) void node_pre(
    const void* __restrict__ node_v, const void* __restrict__ wh,
    const void* __restrict__ wv, const int* __restrict__ flags,
    short* __restrict__ PQ, short* __restrict__ QV)
{
  const int f32m = flags[0];
  int n0 = blockIdx.x * 4, tid = threadIdx.x;
  __shared__ float nv[4][96];
  __shared__ float pq[4][408];
  for (int i = tid; i < 4 * 96; i += 256) nv[i / 96][i % 96] = ldin(node_v, f32m, (long)n0 * 96 + i);
  __syncthreads();
  for (int o = tid; o < 4 * 408; o += 256) {
    int i = o / 408, r0 = o % 408;
    int part = r0 / 204, r = r0 % 204, d = r / 68, h = r % 68;
    int cbase = part ? 36 : 0;
    float acc = 0.f;
#pragma unroll
    for (int c = 0; c < 32; ++c)
      acc += nv[i][c * 3 + d] * ldin(wh, f32m, (cbase + c) * 68 + h);
    pq[i][r0] = acc;
  }
  __syncthreads();
  for (int o = tid; o < 4 * 416; o += 256) {
    int i = o / 416, k = o % 416, part = k / 208, r = k % 208;
    PQ[(long)(n0 + i) * 416 + k] = (r < 204) ? f2bf(pq[i][part * 204 + r]) : (short)0;
  }
  for (int o = tid; o < 4 * 96; o += 256) {
    int i = o / 96, r = o % 96, d = r / 32, c = r % 32;
    float acc = 0.f;
    for (int h = 0; h < 68; ++h)
      acc += pq[i][204 + d * 68 + h] * ldin(wv, f32m, h * 32 + c);
    QV[(long)(n0 + i) * 96 + r] = f2bf(acc);
  }
}

// ---------------------------------------------------------------------------
// edge_node: one block per dst. 8-edge chunks; computes vn (sorted rows, 80
// cols, 68..79 zero), and DIRECT-writes ANS/deg (bf16), AP, AEV. No atomics.
// LDS ~5.7 KB -> high occupancy; pow2 index math only in hot loops.
// ---------------------------------------------------------------------------
__global__ __launch_bounds__(256) void edge_node(
    const void* __restrict__ edge_v, const void* __restrict__ wh,
    const int* __restrict__ flags, const int* __restrict__ rowptr,
    const int* __restrict__ perm, const int* __restrict__ psrc,
    const short* __restrict__ PQ, const short* __restrict__ nsb,
    short* __restrict__ ANSb, float* __restrict__ AP, float* __restrict__ AEV,
    short* __restrict__ vn_out)
{
  const int f32m = flags[0];
  const int n = blockIdx.x, tid = threadIdx.x;
  const int beg = rowptr[n], deg = rowptr[n + 1] - beg;
  __shared__ float Qs[204];
  __shared__ float whs4[272];
  __shared__ __align__(16) short PsL[8 * 208];
  __shared__ float evL[8 * 12];
  __shared__ int svL[8], eidL[8];
  for (int i = tid; i < 204; i += 256) Qs[i] = bf(PQ[(long)n * 416 + 208 + i]);
  for (int i = tid; i < 272; i += 256) whs4[i] = ldin(wh, f32m, (32 + i / 68) * 68 + i % 68);
  float ansc = 0.f, apc = 0.f, aev = 0.f;
  const int pe = tid >> 5, pc = tid & 31;       // P-staging role
  const int ve = tid >> 4, vc = tid & 15;       // ev-staging role
  for (int c0 = 0; c0 < deg; c0 += 8) {
    int m = min(8, deg - c0);
    __syncthreads();                             // protect LDS reuse + svL
    if (tid < m) { svL[tid] = psrc[beg + c0 + tid]; eidL[tid] = perm[beg + c0 + tid]; }
    __syncthreads();
    if (pe < m && pc < 26)
      *(short8*)&PsL[pe * 208 + pc * 8] = *(const short8*)&PQ[(long)svL[pe] * 416 + pc * 8];
    if (tid < 128 && ve < m && vc < 12)
      evL[ve * 12 + vc] = ldin(edge_v, f32m, (long)eidL[ve] * 12 + vc);
    for (int e = 0; e < m; ++e)                  // ANS: coalesced global rows
      ansc += bf(nsb[(long)svL[e] * 256 + tid]);
    __syncthreads();
    // vn: thread -> (e = tid>>5, h = (tid&31) + 32j), rows padded to 80
#pragma unroll
    for (int j = 0; j < 3; ++j) {
      int h = pc + 32 * j;
      if (pe < m && h < 80) {
        float val = 0.f;
        if (h < 68) {
          float ss = 0.f;
#pragma unroll
          for (int d = 0; d < 3; ++d) {
            float v = bf(PsL[pe * 208 + d * 68 + h]) + Qs[d * 68 + h]
                    + evL[pe * 12 + d]     * whs4[h]       + evL[pe * 12 + 3 + d] * whs4[68 + h]
                    + evL[pe * 12 + 6 + d] * whs4[136 + h] + evL[pe * 12 + 9 + d] * whs4[204 + h];
            ss += v * v;
          }
          val = sqrtf(fmaxf(ss, 1e-8f));
        }
        vn_out[(long)(beg + c0 + pe) * 80 + h] = f2bf(val);
      }
    }
    if (tid < 204) {
      for (int e = 0; e < m; ++e) apc += bf(PsL[e * 208 + tid]);
    } else if (tid >= 208 && tid < 220) {
      int c = tid - 208;
      for (int e = 0; e < m; ++e) aev += evL[e * 12 + c];
    }
  }
  float inv = 1.f / fmaxf((float)deg, 1.f);
  ANSb[(long)n * 256 + tid] = f2bf(ansc * inv);
  if (tid < 204) AP[(long)n * 204 + tid] = apc;
  else if (tid >= 208 && tid < 220) AEV[(long)n * 12 + tid - 208] = aev;
}

// ---------------------------------------------------------------------------
// node_gemm: NodeS[n] = [ANS/deg | ns] @ W12  ([N,512]@[512,256]), direct f32.
// 64 rows/block, MFMA 16x16x32, 16 K-slabs.
// ---------------------------------------------------------------------------
__global__ __launch_bounds__(256) void node_gemm(
    const short* __restrict__ ANSb, const short* __restrict__ nsb,
    const short* __restrict__ W12t, float* __restrict__ NodeS)
{
  __shared__ __align__(16) short Xs[64 * 40];
  __shared__ __align__(16) short Ws[256 * 40];
  const int tid = threadIdx.x;
  const int n0 = blockIdx.x * 64;
  const int lane = tid & 63, wave = tid >> 6;
  const int frow = lane & 15, fk = (lane >> 4) * 8, q = lane >> 4;
  f32x4 acc[4][4];
#pragma unroll
  for (int ri = 0; ri < 4; ++ri)
#pragma unroll
    for (int ci = 0; ci < 4; ++ci)
      acc[ri][ci] = (f32x4){0.f, 0.f, 0.f, 0.f};
  const int se = tid >> 2, sq = tid & 3;
  const int rn = min(n0 + se, N_NODES - 1);
  for (int s = 0; s < 16; ++s) {
    short8 xv;
    if (s < 8) xv = *(const short8*)&ANSb[(long)rn * 256 + s * 32 + sq * 8];
    else       xv = *(const short8*)&nsb[(long)rn * 256 + (s - 8) * 32 + sq * 8];
    *(short8*)&Xs[se * 40 + sq * 8] = xv;
#pragma unroll
    for (int it = 0; it < 4; ++it) {
      int flat = it * 256 + tid;
      int nn = flat >> 2, qq = flat & 3;
      *(short8*)&Ws[nn * 40 + qq * 8] = *(const short8*)&W12t[nn * 512 + s * 32 + qq * 8];
    }
    __syncthreads();
    short8 a[4];
#pragma unroll
    for (int ri = 0; ri < 4; ++ri)
      a[ri] = *(const short8*)&Xs[(ri * 16 + frow) * 40 + fk];
#pragma unroll
    for (int ci = 0; ci < 4; ++ci) {
      int nn = wave * 64 + ci * 16 + frow;
      short8 b = *(const short8*)&Ws[nn * 40 + fk];
#pragma unroll
      for (int ri = 0; ri < 4; ++ri)
        acc[ri][ci] = __builtin_amdgcn_mfma_f32_16x16x32_bf16(a[ri], b, acc[ri][ci], 0, 0, 0);
    }
    __syncthreads();
  }
#pragma unroll
  for (int ri = 0; ri < 4; ++ri)
#pragma unroll
    for (int rr = 0; rr < 4; ++rr) {
      int row = n0 + ri * 16 + q * 4 + rr;
      if (row < N_NODES) {
#pragma unroll
        for (int ci = 0; ci < 4; ++ci) {
          int col = wave * 64 + ci * 16 + (lane & 15);
          NodeS[(long)row * 256 + col] = acc[ri][ci][rr];
        }
      }
    }
}

// ---------------------------------------------------------------------------
// gemm_scatter: [E,160] @ Wt3 -> [E,256]; 64 sorted edges/block, 5 K-slabs;
// run-merged atomics into agg_s (edge part only).
// ---------------------------------------------------------------------------
__global__ __launch_bounds__(256) void gemm_scatter(
    const void* __restrict__ edge_s, const short* __restrict__ Wt3,
    const short* __restrict__ vn_ws, const int* __restrict__ perm,
    const int* __restrict__ pdst, const int* __restrict__ flags,
    float* __restrict__ agg_s)
{
  __shared__ __align__(16) short Xs[64 * 40];
  __shared__ __align__(16) short Ws[256 * 40];
  __shared__ int dstv[64], eidv[64];
  const int tid = threadIdx.x;
  const int e0 = blockIdx.x * 64;
  const int f32m = flags[0];
  if (tid < 64) { dstv[tid] = pdst[e0 + tid]; eidv[tid] = perm[e0 + tid]; }
  __syncthreads();
  const int lane = tid & 63, wave = tid >> 6;
  const int frow = lane & 15, fk = (lane >> 4) * 8, q = lane >> 4;
  f32x4 acc[4][4];
#pragma unroll
  for (int ri = 0; ri < 4; ++ri)
#pragma unroll
    for (int ci = 0; ci < 4; ++ci)
      acc[ri][ci] = (f32x4){0.f, 0.f, 0.f, 0.f};
  const int se = tid >> 2, sq = tid & 3;
  for (int s = 0; s < 5; ++s) {
    short8 xv;
    if (s < 2) {
      long off = (long)eidv[se] * 64 + s * 32 + sq * 8;
      if (f32m) {
        const float* pf = (const float*)edge_s + off;
        f32x4 lo = *(const f32x4*)pf, hi = *(const f32x4*)(pf + 4);
        xv[0] = f2bf(lo[0]); xv[1] = f2bf(lo[1]); xv[2] = f2bf(lo[2]); xv[3] = f2bf(lo[3]);
        xv[4] = f2bf(hi[0]); xv[5] = f2bf(hi[1]); xv[6] = f2bf(hi[2]); xv[7] = f2bf(hi[3]);
      } else {
        xv = *(const short8*)((const short*)edge_s + off);
      }
    } else {
      int kk = (s - 2) * 32 + sq * 8;   // 0..95 within vn row (80 stored)
      if (kk < 80) xv = *(const short8*)&vn_ws[(long)(e0 + se) * 80 + kk];
      else { short8 z = {0,0,0,0,0,0,0,0}; xv = z; }
    }
    *(short8*)&Xs[se * 40 + sq * 8] = xv;
#pragma unroll
    for (int it = 0; it < 4; ++it) {
      int flat = it * 256 + tid;
      int nn = flat >> 2, qq = flat & 3;
      *(short8*)&Ws[nn * 40 + qq * 8] = *(const short8*)&Wt3[nn * 160 + s * 32 + qq * 8];
    }
    __syncthreads();
    short8 a[4];
#pragma unroll
    for (int ri = 0; ri < 4; ++ri)
      a[ri] = *(const short8*)&Xs[(ri * 16 + frow) * 40 + fk];
#pragma unroll
    for (int ci = 0; ci < 4; ++ci) {
      int nn = wave * 64 + ci * 16 + frow;
      short8 b = *(const short8*)&Ws[nn * 40 + fk];
#pragma unroll
      for (int ri = 0; ri < 4; ++ri)
        acc[ri][ci] = __builtin_amdgcn_mfma_f32_16x16x32_bf16(a[ri], b, acc[ri][ci], 0, 0, 0);
    }
    __syncthreads();
  }
#pragma unroll
  for (int ci = 0; ci < 4; ++ci) {
    int col = wave * 64 + ci * 16 + (lane & 15);
    float run = 0.f;
    int cur = dstv[4 * q];
#pragma unroll
    for (int ri = 0; ri < 4; ++ri) {
#pragma unroll
      for (int rr = 0; rr < 4; ++rr) {
        int dn = dstv[16 * ri + 4 * q + rr];
        if (dn != cur) {
          atomicAdd(&agg_s[(long)cur * 256 + col], run);
          run = 0.f; cur = dn;
        }
        run += acc[ri][ci][rr];
      }
    }
    atomicAdd(&agg_s[(long)cur * 256 + col], run);
  }
}

// ---------------------------------------------------------------------------
// nodev: agg_v[n] = AP[n] @ wv + AEV[n] @ whv4   (4 nodes/block)
// ---------------------------------------------------------------------------
__global__ __launch_bounds__(256) void nodev_kernel(
    const float* __restrict__ AP, const float* __restrict__ AEV,
    const void* __restrict__ wv, const float* __restrict__ whv4,
    const int* __restrict__ flags, float* __restrict__ agg_v)
{
  const int f32m = flags[0];
  int n0 = blockIdx.x * 4, tid = threadIdx.x;
  __shared__ float wvs[68 * 32];
  __shared__ float wh4s[128];
  __shared__ float APs[4][204];
  __shared__ float AEVs[4][12];
  for (int i = tid; i < 2176; i += 256) wvs[i] = ldin(wv, f32m, i);
  if (tid < 128) wh4s[tid] = whv4[tid];
  for (int i = tid; i < 816; i += 256) APs[i / 204][i % 204] = AP[(long)n0 * 204 + i];
  if (tid < 48) AEVs[tid / 12][tid % 12] = AEV[(long)n0 * 12 + tid];
  __syncthreads();
  for (int o = tid; o < 384; o += 256) {
    int i = o / 96, r = o % 96, c = r / 3, d = r % 3;
    float acc = AEVs[i][d] * wh4s[c] + AEVs[i][3 + d] * wh4s[32 + c]
              + AEVs[i][6 + d] * wh4s[64 + c] + AEVs[i][9 + d] * wh4s[96 + c];
    for (int h = 0; h < 68; ++h)
      acc += APs[i][d * 68 + h] * wvs[h * 32 + c];
    agg_v[(long)(n0 + i) * 96 + r] = acc;
  }
}

// ---------------------------------------------------------------------------
__global__ __launch_bounds__(256) void finalize(
    const float* __restrict__ agg_s, const float* __restrict__ agg_v,
    const int* __restrict__ rowptr, const float* __restrict__ NodeS,
    const short* __restrict__ QV, const void* __restrict__ ws_b,
    const int* __restrict__ flags, void* __restrict__ out)
{
  const int f32m = flags[0];
  int flat = blockIdx.x * 256 + threadIdx.x;   // N*352 exact
  int n = flat / 352, j = flat % 352;
  int deg = rowptr[n + 1] - rowptr[n];
  float inv = 1.f / fmaxf((float)deg, 1.f);
  float v;
  if (j < 256) {
    v = agg_s[(long)n * 256 + j] * inv;
    if (deg > 0) v += NodeS[(long)n * 256 + j] + ldin(ws_b, f32m, j);
  } else {
    int m = j - 256, ch = m / 3, d = m % 3;
    v = agg_v[(long)n * 96 + m] * inv;
    if (deg > 0) v += bf(QV[(long)n * 96 + d * 32 + ch]);
  }
  if (f32m) ((float*)out)[flat] = v;
  else      ((__hip_bfloat16*)out)[flat] = __float2bfloat16(v);
}

extern "C" void kernel_launch(void* const* d_in, const int* in_sizes, int n_in,
                              void* d_out, int out_size, void* d_ws, size_t ws_size,
                              hipStream_t stream) {
  const void* node_s = d_in[0];
  const void* node_v = d_in[1];
  const void* edge_s = d_in[2];
  const void* edge_v = d_in[3];
  const void* wh     = d_in[4];
  const void* ws_w   = d_in[5];
  const void* ws_b   = d_in[6];
  const void* wv     = d_in[7];
  const void* edge_index = d_in[8];

  char* ws = (char*)d_ws;
  float* agg_s = (float*)(ws + AGG_S_OFF);
  int*   hist  = (int*)(ws + HIST_OFF);
  int*   fill  = (int*)(ws + FILL_OFF);
  int*   rowptr= (int*)(ws + ROWPTR_OFF);
  int*   perm  = (int*)(ws + PERM_OFF);
  int*   psrc  = (int*)(ws + PSRC_OFF);
  int*   pdst  = (int*)(ws + PDST_OFF);
  short* PQ    = (short*)(ws + PQ_OFF);
  short* QV    = (short*)(ws + QV_OFF);
  float* whv4  = (float*)(ws + WHV4_OFF);
  short* Wt3   = (short*)(ws + WT3_OFF);
  short* W12t  = (short*)(ws + W12T_OFF);
  short* ns_bf = (short*)(ws + NSBF_OFF);
  float* agg_v = (float*)(ws + AGGV_OFF);   // aliases ns_bf (dead after node_gemm)
  short* ANSb  = (short*)(ws + ANSB_OFF);
  float* AP    = (float*)(ws + AP_OFF);
  float* AEV   = (float*)(ws + AEV_OFF);
  float* NodeS = (float*)(ws + NODES_OFF);
  short* vn    = (short*)(ws + VN_OFF);
  int*   flags = (int*)(ws + FLAGS_OFF);

  hipMemsetAsync(d_ws, 0, ZERO_BYTES, stream);
  detect_kernel<<<1, 256, 0, stream>>>((const unsigned short*)node_s,
                                       (const int*)edge_index, flags);
  hist_kernel<<<1250, 256, 0, stream>>>(edge_index, flags, hist);
  scan_kernel<<<1, 256, 0, stream>>>(hist, rowptr);
  permute_kernel<<<1250, 256, 0, stream>>>(edge_index, flags, rowptr, fill,
                                           perm, psrc, pdst);
  prep_kernel<<<673, 256, 0, stream>>>(ws_w, wh, wv, flags, W12t, Wt3, whv4);
  nsconv_kernel<<<10000, 256, 0, stream>>>(node_s, flags, ns_bf);
  node_pre<<<2500, 256, 0, stream>>>(node_v, wh, wv, flags, PQ, QV);
  edge_node<<<10000, 256, 0, stream>>>(edge_v, wh, flags, rowptr, perm, psrc,
                                       PQ, ns_bf, ANSb, AP, AEV, vn);
  node_gemm<<<158, 256, 0, stream>>>(ANSb, ns_bf, W12t, NodeS);
  gemm_scatter<<<5000, 256, 0, stream>>>(edge_s, Wt3, vn, perm, pdst, flags,
                                         agg_s);
  nodev_kernel<<<2500, 256, 0, stream>>>(AP, AEV, wv, whv4, flags, agg_v);
  finalize<<<13750, 256, 0, stream>>>(agg_s, agg_v, rowptr, NodeS, QV, ws_b,
                                      flags, d_out);
}

// Round 7
// 505.781 us; speedup vs baseline: 1.4359x; 1.1407x over previous
//
#include <hip/hip_runtime.h>
#include <hip/hip_bf16.h>

#define N_NODES 10000
#define E_TOT   320000

typedef __attribute__((ext_vector_type(8))) short short8;
typedef __attribute__((ext_vector_type(4))) float f32x4;

// ---- workspace byte offsets (16B-aligned; total ~49.4 MB) ----
#define HIST_OFF    0u            // N int (zeroed)
#define FILL_OFF    40000u        // N int (zeroed)
#define ZERO_BYTES  80000u        // memset [0, here) -- only the sort counters!
#define ROWPTR_OFF  80000u        // (N+1) int (fully written by scan)
#define PERM_OFF    120064u       // E int
#define PSRC_OFF    1400064u      // E int
#define PQ_OFF      2680064u      // N*416 bf16 [P(204)+pad | Q(204)+pad]
#define QV_OFF      11000064u     // N*96 bf16
#define WHV4_OFF    12920064u     // 128 f32
#define WBIG_OFF    12920576u     // 256*672 bf16 = 344,064  mega scalar GEMM W^T
#define NSBF_OFF    13264640u     // N*256 bf16
#define ANSB_OFF    18384640u     // N*256 bf16  (sum ns[src])/deg
#define EAB_OFF     23504640u     // N*160 bf16  [AES(64)|AVN(68)|pad(28)]/deg
#define AP_OFF      26704640u     // N*204 f32   sum P[src]
#define AEV_OFF     34864640u     // N*12 f32    sum edge_v
#define NODES_OFF   35344640u     // N*256 f32   scalar output pre-bias
#define AGGV_OFF    45584640u     // N*96 f32
#define FLAGS_OFF   49424640u     // 2 ints

union BfS { __hip_bfloat16 h; short s; };
__device__ __forceinline__ short f2bf(float x) { BfS u; u.h = __float2bfloat16(x); return u.s; }
__device__ __forceinline__ float bf(short x) { BfS u; u.s = x; return __bfloat162float(u.h); }
__device__ __forceinline__ float ldin(const void* p, int f32m, long i) {
  return f32m ? ((const float*)p)[i] : __bfloat162float(((const __hip_bfloat16*)p)[i]);
}
__device__ __forceinline__ int get_ei(const void* p, int i64m, long i) {
  return i64m ? (int)(((const long long*)p)[i]) : ((const int*)p)[i];
}

// ---------------------------------------------------------------------------
__global__ __launch_bounds__(256) void detect_kernel(
    const unsigned short* __restrict__ ns_u16,
    const int* __restrict__ ei_i32, int* __restrict__ flags)
{
  __shared__ int cf, ci;
  if (threadIdx.x == 0) { cf = 0; ci = 0; }
  __syncthreads();
  int c1 = 0;
  for (int i = threadIdx.x; i < 8192; i += 256) {
    unsigned e = (ns_u16[2 * i] >> 7) & 0xFF;
    if (e < 100 || e > 140) c1++;
  }
  int c2 = 0;
  for (int i = threadIdx.x; i < 4096; i += 256)
    if (ei_i32[2 * i + 1] != 0) c2++;
  atomicAdd(&cf, c1); atomicAdd(&ci, c2);
  __syncthreads();
  if (threadIdx.x == 0) {
    flags[0] = (cf > 512) ? 1 : 0;   // 1 => f32 inputs
    flags[1] = (ci < 100) ? 1 : 0;   // 1 => int64 edge_index
  }
}

// ---------------------------------------------------------------------------
__global__ __launch_bounds__(256) void hist_kernel(
    const void* __restrict__ edge_index, const int* __restrict__ flags,
    int* __restrict__ hist)
{
  const int i64m = flags[1];
  int e = blockIdx.x * 256 + threadIdx.x;
  int dst = get_ei(edge_index, i64m, (long)E_TOT + e);
  atomicAdd(&hist[dst], 1);
}

__global__ __launch_bounds__(256) void scan_kernel(
    const int* __restrict__ hist, int* __restrict__ rowptr)
{
  __shared__ int part[256];
  int tid = threadIdx.x;
  int base = tid * 40;
  int s = 0;
  for (int i = 0; i < 40; ++i) { int idx = base + i; if (idx < N_NODES) s += hist[idx]; }
  part[tid] = s;
  __syncthreads();
  for (int off = 1; off < 256; off <<= 1) {
    int v = (tid >= off) ? part[tid - off] : 0;
    __syncthreads();
    part[tid] += v;
    __syncthreads();
  }
  int run = (tid > 0) ? part[tid - 1] : 0;
  for (int i = 0; i < 40; ++i) {
    int idx = base + i;
    if (idx < N_NODES) { rowptr[idx] = run; run += hist[idx]; }
  }
  if (tid == 255) rowptr[N_NODES] = run;
}

__global__ __launch_bounds__(256) void permute_kernel(
    const void* __restrict__ edge_index, const int* __restrict__ flags,
    const int* __restrict__ rowptr, int* __restrict__ fill,
    int* __restrict__ perm, int* __restrict__ psrc)
{
  const int i64m = flags[1];
  int e = blockIdx.x * 256 + threadIdx.x;
  int dst = get_ei(edge_index, i64m, (long)E_TOT + e);
  int src = get_ei(edge_index, i64m, e);
  int pos = rowptr[dst] + atomicAdd(&fill[dst], 1);
  perm[pos] = e; psrc[pos] = src;
}

// ---------------------------------------------------------------------------
// prep: Wbig^T[o][k<672]: k<320 -> ws_w row k (src ns + edge_s);
//       320..387 -> rows 576..643 (vn); 388..415 -> 0; 416..671 -> rows
//       320..575 (dst ns, i.e. r = k-96). Block 672: whv4 = wh[32:36]@wv.
// ---------------------------------------------------------------------------
__global__ __launch_bounds__(256) void prep_kernel(
    const void* __restrict__ ws_w, const void* __restrict__ wh,
    const void* __restrict__ wv, const int* __restrict__ flags,
    short* __restrict__ Wbig, float* __restrict__ whv4)
{
  const int f32m = flags[0];
  int b = blockIdx.x, tid = threadIdx.x;
  if (b < 672) {
    int flat = b * 256 + tid;           // = o*672 + k
    int o = flat / 672, k = flat % 672;
    short v = 0;
    if (k < 320)      v = f2bf(ldin(ws_w, f32m, (long)k * 256 + o));
    else if (k < 388) v = f2bf(ldin(ws_w, f32m, (long)(576 + k - 320) * 256 + o));
    else if (k >= 416) v = f2bf(ldin(ws_w, f32m, (long)(k - 96) * 256 + o));
    Wbig[flat] = v;
  } else if (tid < 128) {
    int q = tid / 32, c = tid % 32;
    float acc = 0.f;
    for (int h = 0; h < 68; ++h)
      acc += ldin(wh, f32m, (32 + q) * 68 + h) * ldin(wv, f32m, h * 32 + c);
    whv4[tid] = acc;
  }
}

__global__ __launch_bounds__(256) void nsconv_kernel(
    const void* __restrict__ node_s, const int* __restrict__ flags,
    short* __restrict__ ns_bf)
{
  const int f32m = flags[0];
  int i = blockIdx.x * 256 + threadIdx.x;
  ns_bf[i] = f2bf(ldin(node_s, f32m, i));
}

// ---------------------------------------------------------------------------
// node_pre: per 4 nodes — PQ = [P|Q] bf16 (padded 208 each), Qv bf16.
// ---------------------------------------------------------------------------
__global__ __launch_bounds__(256) void node_pre(
    const void* __restrict__ node_v, const void* __restrict__ wh,
    const void* __restrict__ wv, const int* __restrict__ flags,
    short* __restrict__ PQ, short* __restrict__ QV)
{
  const int f32m = flags[0];
  int n0 = blockIdx.x * 4, tid = threadIdx.x;
  __shared__ float nv[4][96];
  __shared__ float pq[4][408];
  for (int i = tid; i < 4 * 96; i += 256) nv[i / 96][i % 96] = ldin(node_v, f32m, (long)n0 * 96 + i);
  __syncthreads();
  for (int o = tid; o < 4 * 408; o += 256) {
    int i = o / 408, r0 = o % 408;
    int part = r0 / 204, r = r0 % 204, d = r / 68, h = r % 68;
    int cbase = part ? 36 : 0;
    float acc = 0.f;
#pragma unroll
    for (int c = 0; c < 32; ++c)
      acc += nv[i][c * 3 + d] * ldin(wh, f32m, (cbase + c) * 68 + h);
    pq[i][r0] = acc;
  }
  __syncthreads();
  for (int o = tid; o < 4 * 416; o += 256) {
    int i = o / 416, k = o % 416, part = k / 208, r = k % 208;
    PQ[(long)(n0 + i) * 416 + k] = (r < 204) ? f2bf(pq[i][part * 204 + r]) : (short)0;
  }
  for (int o = tid; o < 4 * 96; o += 256) {
    int i = o / 96, r = o % 96, d = r / 32, c = r % 32;
    float acc = 0.f;
    for (int h = 0; h < 68; ++h)
      acc += pq[i][204 + d * 68 + h] * ldin(wv, f32m, h * 32 + c);
    QV[(long)(n0 + i) * 96 + r] = f2bf(acc);
  }
}

// ---------------------------------------------------------------------------
// edge_node: one block per dst. 8-edge chunks; vn computed IN LDS ONLY.
// Direct-writes (no atomics, no global vn): ANS/deg, [AES|AVN]/deg, AP, AEV.
// ---------------------------------------------------------------------------
__global__ __launch_bounds__(256) void edge_node(
    const void* __restrict__ edge_v, const void* __restrict__ edge_s,
    const void* __restrict__ wh, const int* __restrict__ flags,
    const int* __restrict__ rowptr, const int* __restrict__ perm,
    const int* __restrict__ psrc, const short* __restrict__ PQ,
    const short* __restrict__ nsb,
    short* __restrict__ ANSb, short* __restrict__ EAb,
    float* __restrict__ AP, float* __restrict__ AEV)
{
  const int f32m = flags[0];
  const int n = blockIdx.x, tid = threadIdx.x;
  const int beg = rowptr[n], deg = rowptr[n + 1] - beg;
  __shared__ float Qs[204];
  __shared__ float whs4[272];
  __shared__ __align__(16) short PsL[8 * 208];
  __shared__ float evL[8 * 12];
  __shared__ float esL[8 * 64];
  __shared__ float vnL[8 * 68];
  __shared__ int svL[8], eidL[8];
  for (int i = tid; i < 204; i += 256) Qs[i] = bf(PQ[(long)n * 416 + 208 + i]);
  for (int i = tid; i < 272; i += 256) whs4[i] = ldin(wh, f32m, (32 + i / 68) * 68 + i % 68);
  float ansc = 0.f, apc = 0.f, aev = 0.f, aesc = 0.f, avnc = 0.f;
  const int pe = tid >> 5, pc = tid & 31;
  for (int c0 = 0; c0 < deg; c0 += 8) {
    int m = min(8, deg - c0);
    __syncthreads();                 // B1: prev-iter LDS readers done
    if (tid < m) { svL[tid] = psrc[beg + c0 + tid]; eidL[tid] = perm[beg + c0 + tid]; }
    __syncthreads();                 // B2: indices ready
    if (pe < m && pc < 26)
      *(short8*)&PsL[pe * 208 + pc * 8] = *(const short8*)&PQ[(long)svL[pe] * 416 + pc * 8];
    for (int i = tid; i < m * 12; i += 256)
      evL[i] = ldin(edge_v, f32m, (long)eidL[i / 12] * 12 + i % 12);
    for (int i = tid; i < m * 64; i += 256)
      esL[i] = ldin(edge_s, f32m, (long)eidL[i >> 6] * 64 + (i & 63));
    for (int e = 0; e < m; ++e)      // ANS gather (coalesced 512B rows, L2)
      ansc += bf(nsb[(long)svL[e] * 256 + tid]);
    __syncthreads();                 // B3: staging ready
    // vn -> vnL
#pragma unroll
    for (int j = 0; j < 3; ++j) {
      int h = pc + 32 * j;
      if (pe < m && h < 68) {
        float ss = 0.f;
#pragma unroll
        for (int d = 0; d < 3; ++d) {
          float v = bf(PsL[pe * 208 + d * 68 + h]) + Qs[d * 68 + h]
                  + evL[pe * 12 + d]     * whs4[h]       + evL[pe * 12 + 3 + d] * whs4[68 + h]
                  + evL[pe * 12 + 6 + d] * whs4[136 + h] + evL[pe * 12 + 9 + d] * whs4[204 + h];
          ss += v * v;
        }
        vnL[pe * 68 + h] = sqrtf(fmaxf(ss, 1e-8f));
      }
    }
    if (tid < 204) { for (int e = 0; e < m; ++e) apc += bf(PsL[e * 208 + tid]); }
    else if (tid < 216) { int c = tid - 204; for (int e = 0; e < m; ++e) aev += evL[e * 12 + c]; }
    if (tid < 64)  { for (int e = 0; e < m; ++e) aesc += esL[e * 64 + tid]; }
    __syncthreads();                 // B4: vnL ready
    if (tid < 68)  { for (int e = 0; e < m; ++e) avnc += vnL[e * 68 + tid]; }
  }
  float inv = 1.f / fmaxf((float)deg, 1.f);
  ANSb[(long)n * 256 + tid] = f2bf(ansc * inv);
  if (tid < 204) AP[(long)n * 204 + tid] = apc;
  else if (tid < 216) AEV[(long)n * 12 + tid - 204] = aev;
  if (tid < 64) EAb[(long)n * 160 + tid] = f2bf(aesc * inv);
  if (tid < 68) EAb[(long)n * 160 + 64 + tid] = f2bf(avnc * inv);
  if (tid >= 132 && tid < 160) EAb[(long)n * 160 + tid] = 0;
}

// ---------------------------------------------------------------------------
// node_gemm: NodeS[n] = [ANS/deg | AES/deg|AVN/deg | ns] @ Wbig
// ([N,672]@[672,256]); 64 rows/block, 21 K-slabs, direct f32 stores.
// ---------------------------------------------------------------------------
__global__ __launch_bounds__(256) void node_gemm(
    const short* __restrict__ ANSb, const short* __restrict__ EAb,
    const short* __restrict__ nsb, const short* __restrict__ Wbig,
    float* __restrict__ NodeS)
{
  __shared__ __align__(16) short Xs[64 * 40];
  __shared__ __align__(16) short Ws[256 * 40];
  const int tid = threadIdx.x;
  const int n0 = blockIdx.x * 64;
  const int lane = tid & 63, wave = tid >> 6;
  const int frow = lane & 15, fk = (lane >> 4) * 8, q = lane >> 4;
  f32x4 acc[4][4];
#pragma unroll
  for (int ri = 0; ri < 4; ++ri)
#pragma unroll
    for (int ci = 0; ci < 4; ++ci)
      acc[ri][ci] = (f32x4){0.f, 0.f, 0.f, 0.f};
  const int se = tid >> 2, sq = tid & 3;
  const int rn = min(n0 + se, N_NODES - 1);
  for (int s = 0; s < 21; ++s) {
    short8 xv;
    if (s < 8)       xv = *(const short8*)&ANSb[(long)rn * 256 + s * 32 + sq * 8];
    else if (s < 13) xv = *(const short8*)&EAb[(long)rn * 160 + (s - 8) * 32 + sq * 8];
    else             xv = *(const short8*)&nsb[(long)rn * 256 + (s - 13) * 32 + sq * 8];
    *(short8*)&Xs[se * 40 + sq * 8] = xv;
#pragma unroll
    for (int it = 0; it < 4; ++it) {
      int flat = it * 256 + tid;
      int nn = flat >> 2, qq = flat & 3;
      *(short8*)&Ws[nn * 40 + qq * 8] = *(const short8*)&Wbig[nn * 672 + s * 32 + qq * 8];
    }
    __syncthreads();
    short8 a[4];
#pragma unroll
    for (int ri = 0; ri < 4; ++ri)
      a[ri] = *(const short8*)&Xs[(ri * 16 + frow) * 40 + fk];
#pragma unroll
    for (int ci = 0; ci < 4; ++ci) {
      int nn = wave * 64 + ci * 16 + frow;
      short8 b = *(const short8*)&Ws[nn * 40 + fk];
#pragma unroll
      for (int ri = 0; ri < 4; ++ri)
        acc[ri][ci] = __builtin_amdgcn_mfma_f32_16x16x32_bf16(a[ri], b, acc[ri][ci], 0, 0, 0);
    }
    __syncthreads();
  }
#pragma unroll
  for (int ri = 0; ri < 4; ++ri)
#pragma unroll
    for (int rr = 0; rr < 4; ++rr) {
      int row = n0 + ri * 16 + q * 4 + rr;
      if (row < N_NODES) {
#pragma unroll
        for (int ci = 0; ci < 4; ++ci) {
          int col = wave * 64 + ci * 16 + (lane & 15);
          NodeS[(long)row * 256 + col] = acc[ri][ci][rr];
        }
      }
    }
}

// ---------------------------------------------------------------------------
// nodev: agg_v[n] = AP[n] @ wv + AEV[n] @ whv4   (4 nodes/block)
// ---------------------------------------------------------------------------
__global__ __launch_bounds__(256) void nodev_kernel(
    const float* __restrict__ AP, const float* __restrict__ AEV,
    const void* __restrict__ wv, const float* __restrict__ whv4,
    const int* __restrict__ flags, float* __restrict__ agg_v)
{
  const int f32m = flags[0];
  int n0 = blockIdx.x * 4, tid = threadIdx.x;
  __shared__ float wvs[68 * 32];
  __shared__ float wh4s[128];
  __shared__ float APs[4][204];
  __shared__ float AEVs[4][12];
  for (int i = tid; i < 2176; i += 256) wvs[i] = ldin(wv, f32m, i);
  if (tid < 128) wh4s[tid] = whv4[tid];
  for (int i = tid; i < 816; i += 256) APs[i / 204][i % 204] = AP[(long)n0 * 204 + i];
  if (tid < 48) AEVs[tid / 12][tid % 12] = AEV[(long)n0 * 12 + tid];
  __syncthreads();
  for (int o = tid; o < 384; o += 256) {
    int i = o / 96, r = o % 96, c = r / 3, d = r % 3;
    float acc = AEVs[i][d] * wh4s[c] + AEVs[i][3 + d] * wh4s[32 + c]
              + AEVs[i][6 + d] * wh4s[64 + c] + AEVs[i][9 + d] * wh4s[96 + c];
    for (int h = 0; h < 68; ++h)
      acc += APs[i][d * 68 + h] * wvs[h * 32 + c];
    agg_v[(long)(n0 + i) * 96 + r] = acc;
  }
}

// ---------------------------------------------------------------------------
__global__ __launch_bounds__(256) void finalize(
    const float* __restrict__ NodeS, const float* __restrict__ agg_v,
    const int* __restrict__ rowptr, const short* __restrict__ QV,
    const void* __restrict__ ws_b, const int* __restrict__ flags,
    void* __restrict__ out)
{
  const int f32m = flags[0];
  int flat = blockIdx.x * 256 + threadIdx.x;   // N*352 exact
  int n = flat / 352, j = flat % 352;
  int deg = rowptr[n + 1] - rowptr[n];
  float v;
  if (j < 256) {
    v = (deg > 0) ? (NodeS[(long)n * 256 + j] + ldin(ws_b, f32m, j)) : 0.f;
  } else {
    int m = j - 256, ch = m / 3, d = m % 3;
    float inv = 1.f / fmaxf((float)deg, 1.f);
    v = agg_v[(long)n * 96 + m] * inv;
    if (deg > 0) v += bf(QV[(long)n * 96 + d * 32 + ch]);
  }
  if (f32m) ((float*)out)[flat] = v;
  else      ((__hip_bfloat16*)out)[flat] = __float2bfloat16(v);
}

extern "C" void kernel_launch(void* const* d_in, const int* in_sizes, int n_in,
                              void* d_out, int out_size, void* d_ws, size_t ws_size,
                              hipStream_t stream) {
  const void* node_s = d_in[0];
  const void* node_v = d_in[1];
  const void* edge_s = d_in[2];
  const void* edge_v = d_in[3];
  const void* wh     = d_in[4];
  const void* ws_w   = d_in[5];
  const void* ws_b   = d_in[6];
  const void* wv     = d_in[7];
  const void* edge_index = d_in[8];

  char* ws = (char*)d_ws;
  int*   hist  = (int*)(ws + HIST_OFF);
  int*   fill  = (int*)(ws + FILL_OFF);
  int*   rowptr= (int*)(ws + ROWPTR_OFF);
  int*   perm  = (int*)(ws + PERM_OFF);
  int*   psrc  = (int*)(ws + PSRC_OFF);
  short* PQ    = (short*)(ws + PQ_OFF);
  short* QV    = (short*)(ws + QV_OFF);
  float* whv4  = (float*)(ws + WHV4_OFF);
  short* Wbig  = (short*)(ws + WBIG_OFF);
  short* ns_bf = (short*)(ws + NSBF_OFF);
  short* ANSb  = (short*)(ws + ANSB_OFF);
  short* EAb   = (short*)(ws + EAB_OFF);
  float* AP    = (float*)(ws + AP_OFF);
  float* AEV   = (float*)(ws + AEV_OFF);
  float* NodeS = (float*)(ws + NODES_OFF);
  float* agg_v = (float*)(ws + AGGV_OFF);
  int*   flags = (int*)(ws + FLAGS_OFF);

  hipMemsetAsync(d_ws, 0, ZERO_BYTES, stream);
  detect_kernel<<<1, 256, 0, stream>>>((const unsigned short*)node_s,
                                       (const int*)edge_index, flags);
  hist_kernel<<<1250, 256, 0, stream>>>(edge_index, flags, hist);
  scan_kernel<<<1, 256, 0, stream>>>(hist, rowptr);
  permute_kernel<<<1250, 256, 0, stream>>>(edge_index, flags, rowptr, fill,
                                           perm, psrc);
  prep_kernel<<<673, 256, 0, stream>>>(ws_w, wh, wv, flags, Wbig, whv4);
  nsconv_kernel<<<10000, 256, 0, stream>>>(node_s, flags, ns_bf);
  node_pre<<<2500, 256, 0, stream>>>(node_v, wh, wv, flags, PQ, QV);
  edge_node<<<10000, 256, 0, stream>>>(edge_v, edge_s, wh, flags, rowptr,
                                       perm, psrc, PQ, ns_bf,
                                       ANSb, EAb, AP, AEV);
  node_gemm<<<157, 256, 0, stream>>>(ANSb, EAb, ns_bf, Wbig, NodeS);
  nodev_kernel<<<2500, 256, 0, stream>>>(AP, AEV, wv, whv4, flags, agg_v);
  finalize<<<13750, 256, 0, stream>>>(NodeS, agg_v, rowptr, QV, ws_b,
                                      flags, d_out);
}